// Round 4
// baseline (102.672 us; speedup 1.0000x reference)
//
#include <hip/hip_runtime.h>

#define INFV 1000000000.0f
#define EPSV 1e-6f
#define DPITCH 35        // dist grid pitch (odd -> lane-stride-35 conflict-free)
#define DSZ    1192      // 34*35 = 1190, padded to 1192 (16B multiple)
#define WPITCH 33        // weight pitch (odd -> conflict-free both orientations)
#define WSZ    1056      // 32*33

// One fast-sweep pass along 32 parallel lines (one line per lane).
// GA = stride along the line in the dist grid, GPERP = stride to the two
// perpendicular neighbor lines, WA = stride along the line in the weight grid.
// Update per cell: nd = min(cur, fl(w + min(8 neighbors))) — identical float
// algebra to the reference (single add of the min), so the least fixed point
// is bit-identical to the reference's 1024 Jacobi sweeps (monotone operator,
// chaotic-iteration convergence; certified by a full no-change sweep).
template<int GA, int GPERP, int WA, bool FWD>
__device__ __forceinline__ float sweep_line(float* g, const float* wg,
                                            int go, int wo) {
    float up[34], dn[34], cur[32], wv[32];
#pragma unroll
    for (int i = 0; i < 34; ++i) {
        up[i] = g[go - GPERP + (i - 1) * GA];
        dn[i] = g[go + GPERP + (i - 1) * GA];
    }
#pragma unroll
    for (int i = 0; i < 32; ++i) cur[i] = g[go + i * GA];
#pragma unroll
    for (int i = 0; i < 32; ++i) wv[i] = wg[wo + i * WA];

    float mxs = 0.0f;
    float prev = INFV;
    if (FWD) {
#pragma unroll
        for (int i = 0; i < 32; ++i) {
            const float opp = (i < 31) ? cur[i + 1] : INFV;   // old value (Jacobi side)
            const float pm = fminf(fminf(up[i], up[i + 1]), up[i + 2]);
            const float qm = fminf(fminf(dn[i], dn[i + 1]), dn[i + 2]);
            const float m  = fminf(fminf(pm, qm), fminf(opp, prev));
            const float nd = fminf(cur[i], wv[i] + m);        // one add of the min, as ref
            mxs = fmaxf(mxs, cur[i] - nd);                    // >0 iff changed (monotone)
            cur[i] = nd;
            prev = nd;                                        // GS along the line
        }
    } else {
#pragma unroll
        for (int i = 31; i >= 0; --i) {
            const float opp = (i > 0) ? cur[i - 1] : INFV;
            const float pm = fminf(fminf(up[i], up[i + 1]), up[i + 2]);
            const float qm = fminf(fminf(dn[i], dn[i + 1]), dn[i + 2]);
            const float m  = fminf(fminf(pm, qm), fminf(opp, prev));
            const float nd = fminf(cur[i], wv[i] + m);
            mxs = fmaxf(mxs, cur[i] - nd);
            cur[i] = nd;
            prev = nd;
        }
    }
#pragma unroll
    for (int i = 0; i < 32; ++i) g[go + i * GA] = cur[i];
    return mxs;
}

// One wave per block, 2 batches per wave: lanes 0-31 = batch A, 32-63 = batch B.
// Lane r owns row r (row phases) or column r (column phases) of its batch.
// Single wave -> lockstep; no barriers needed in the sweep loop (LDS pipe is
// in-order per wave, compiler cannot reorder aliasing LDS ops).
__global__ __launch_bounds__(64)
void bbastar_kernel(const float* __restrict__ weights,
                    const int* __restrict__ source,
                    const int* __restrict__ target,
                    float* __restrict__ out) {
    __shared__ float g[2][DSZ];    // dist, cell (r,c) at (r+1)*35 + c+1; halo ring = INFV
    __shared__ float wg[2][WSZ];   // weights+EPS, cell (r,c) at r*33 + c

    const int lane = threadIdx.x;
    const int sb   = lane >> 5;
    const int r    = lane & 31;
    const int gb   = blockIdx.x * 2 + sb;

    // zero this block's output region (harness poisons d_out with 0xAA)
    {
        const float4 z = make_float4(0.f, 0.f, 0.f, 0.f);
        float4* og = (float4*)(out + (size_t)blockIdx.x * 2048);
#pragma unroll
        for (int i = 0; i < 8; ++i) og[lane + (i << 6)] = z;
    }
    // stage weights (+EPS, single f32 add as reference) into LDS, coalesced reads
    {
        const float4* wgl = (const float4*)(weights + (size_t)blockIdx.x * 2048);
#pragma unroll
        for (int i = 0; i < 8; ++i) {
            const int idx = lane + (i << 6);          // 0..511 float4s
            const float4 v = wgl[idx];
            const int fi = idx << 2;
            const int bb = fi >> 10;
            const int rr = (fi >> 5) & 31;
            const int cc = fi & 31;
            float* p = &wg[bb][rr * WPITCH + cc];     // b32 stores (pitch 33 unaligned for b128)
            p[0] = v.x + EPSV; p[1] = v.y + EPSV; p[2] = v.z + EPSV; p[3] = v.w + EPSV;
        }
    }
    // INF-fill dist (both batches, incl. halo ring)
    {
        const float4 inf4 = make_float4(INFV, INFV, INFV, INFV);
        float4* df = (float4*)&g[0][0];               // 2*1192/4 = 596 float4s
#pragma unroll
        for (int i = 0; i < 10; ++i) {
            const int idx = lane + (i << 6);
            if (idx < 596) df[idx] = inf4;
        }
    }
    __syncthreads();

    const int sr = source[2 * gb], sc = source[2 * gb + 1];
    if (r == 0)   // lanes 0 and 32 seed their batch's source cell
        g[sb][(sr + 1) * DPITCH + sc + 1] = wg[sb][sr * WPITCH + sc];
    __syncthreads();

    float* gp = g[sb];
    const float* wp = wg[sb];
    const int growo = (r + 1) * DPITCH + 1;   // row r, col 0
    const int wrowo = r * WPITCH;
    const int gcolo = DPITCH + r + 1;         // row 0, col r
    const int wcolo = r;

    // 4-orientation fast sweeping: row L->R, col T->B, row R->L, col B->T.
    // GS along the line (registers), Jacobi across lines (lockstep lanes).
    for (int it = 0; it < 1024; ++it) {
        float mxs;
        switch (it & 3) {
            case 0:  mxs = sweep_line<1, DPITCH, 1,      true >(gp, wp, growo, wrowo); break;
            case 1:  mxs = sweep_line<DPITCH, 1, WPITCH, true >(gp, wp, gcolo, wcolo); break;
            case 2:  mxs = sweep_line<1, DPITCH, 1,      false>(gp, wp, growo, wrowo); break;
            default: mxs = sweep_line<DPITCH, 1, WPITCH, false>(gp, wp, gcolo, wcolo); break;
        }
        if (__ballot(mxs > 0.0f) == 0ULL) break;   // full no-change sweep = fixed point
    }
    __syncthreads();

    // Greedy backtrack, lanes 0 (batch A) and 32 (batch B) concurrently.
    // Halo ring holds exactly INFV = reference's where(valid, ., INF); strict '<'
    // scan in OFFS order replicates jnp.argmin first-min tie-breaking.
    if (r == 0) {
        const int drr[8] = {-1, -1, -1,  0, 0,  1, 1, 1};
        const int dcc[8] = {-1,  0,  1, -1, 1, -1, 0, 1};
        int pr = target[2 * gb], pc = target[2 * gb + 1];
        float* ob = out + (size_t)gb * 1024;
        for (int step = 0; step < 1024; ++step) {
            ob[pr * 32 + pc] = 1.0f;
            if (pr == sr && pc == sc) break;
            float best = INFV; int bj = 0;
#pragma unroll
            for (int j = 0; j < 8; ++j) {
                const float v = gp[(pr + drr[j] + 1) * DPITCH + (pc + dcc[j] + 1)];
                if (v < best) { best = v; bj = j; }
            }
            pr += drr[bj];
            pc += dcc[bj];
        }
    }
}

extern "C" void kernel_launch(void* const* d_in, const int* in_sizes, int n_in,
                              void* d_out, int out_size, void* d_ws, size_t ws_size,
                              hipStream_t stream) {
    const float* weights = (const float*)d_in[0];
    const int*   source  = (const int*)d_in[1];
    const int*   target  = (const int*)d_in[2];
    float*       out     = (float*)d_out;
    const int B = in_sizes[0] / 1024;
    bbastar_kernel<<<B / 2, 64, 0, stream>>>(weights, source, target, out);
}

// Round 5
// 82.317 us; speedup vs baseline: 1.2473x; 1.2473x over previous
//
#include <hip/hip_runtime.h>

#define INFV 1000000000.0f
#define EPSV 1e-6f
#define DP   35        // dist pitch (odd): row-phase lane stride 35, col-phase 1 -> <=2-way banks (free)
#define DSZ  1192      // 34*35 = 1190, padded to multiple of 4
#define WP   33        // weight pitch (odd), staging only
#define WSZ  1056      // 32*33

// One chunked fast-sweep subpass along 32 parallel lines, 2 chunks/line.
// GA = stride along line, GP = stride to neighbor lines. wbase = LDS addr of
// cell (line, 16h-1) — the 18-window covers chunk + both boundary cells
// (grid halo ring holds exactly INFV = reference's where(valid,.,INF)).
// Update: nd = min(cur, fl(w + min(8 nbrs))) — identical float algebra to the
// reference: min(fl(w+a), fl(w+b)) == fl(w + min(a,b)) by rounding
// monotonicity, so splitting the GS 'prev' term off is exact. Monotone
// operator + chaotic iteration -> unique least fixed point, certified by one
// full no-change subpass; bit-identical to the reference's 1024 Jacobi sweeps.
template<int GA, int GP, bool FWD>
__device__ __forceinline__ float subpass(float* __restrict__ g,
                                         const int wbase,
                                         const float* __restrict__ w) {
    float up[18], dn[18], cx[18];
#pragma unroll
    for (int j = 0; j < 18; ++j) up[j] = g[wbase - GP + j * GA];
#pragma unroll
    for (int j = 0; j < 18; ++j) dn[j] = g[wbase + GP + j * GA];
#pragma unroll
    for (int j = 0; j < 18; ++j) cx[j] = g[wbase + j * GA];
    float nc[16];
    float mx = 0.0f;
    if (FWD) {
        float prev = cx[0];                       // old left boundary (halo/Jacobi)
#pragma unroll
        for (int j = 0; j < 16; ++j) {
            const float pm  = fminf(fminf(up[j], up[j + 1]), up[j + 2]);
            const float qm  = fminf(fminf(dn[j], dn[j + 1]), dn[j + 2]);
            const float off = fminf(fminf(pm, qm), cx[j + 2]);   // old right (Jacobi)
            const float pre = fminf(cx[j + 1], w[j] + off);      // off-chain
            const float nd  = fminf(pre, w[j] + prev);           // chain: add+min
            mx = fmaxf(mx, cx[j + 1] - nd);                      // >0 iff changed
            nc[j] = nd;
            prev  = nd;                                          // GS along line
        }
    } else {
        float prev = cx[17];                      // old right boundary
#pragma unroll
        for (int j = 15; j >= 0; --j) {
            const float pm  = fminf(fminf(up[j], up[j + 1]), up[j + 2]);
            const float qm  = fminf(fminf(dn[j], dn[j + 1]), dn[j + 2]);
            const float off = fminf(fminf(pm, qm), cx[j]);       // old left (Jacobi)
            const float pre = fminf(cx[j + 1], w[j] + off);
            const float nd  = fminf(pre, w[j] + prev);
            mx = fmaxf(mx, cx[j + 1] - nd);
            nc[j] = nd;
            prev  = nd;
        }
    }
#pragma unroll
    for (int j = 0; j < 16; ++j) g[wbase + (j + 1) * GA] = nc[j];
    return mx;
}

// One batch per block, ONE wave: lane = (line = lane&31, half = lane>>5).
// Row phases: lane owns cells (row=line, cols 16h..16h+15); col phases:
// (rows 16h..16h+15, col=line). Single wave -> lockstep, LDS pipe in-order,
// no barriers in the sweep loop.
__global__ __launch_bounds__(64)
void bbastar_kernel(const float* __restrict__ weights,
                    const int* __restrict__ source,
                    const int* __restrict__ target,
                    float* __restrict__ out) {
    __shared__ float g[DSZ];     // dist; cell (r,c) at (r+1)*DP + (c+1); halo = INFV
    __shared__ float wl[WSZ];    // weights+EPS staging; cell (r,c) at r*WP + c

    const int lane = threadIdx.x;
    const int line = lane & 31;
    const int h    = lane >> 5;
    const int gb   = blockIdx.x;

    // zero this batch's output (harness poisons d_out with 0xAA)
    {
        const float4 z = make_float4(0.f, 0.f, 0.f, 0.f);
        float4* og = (float4*)(out + (size_t)gb * 1024);
#pragma unroll
        for (int i = 0; i < 4; ++i) og[lane + (i << 6)] = z;
    }
    // stage weights (+EPS, single f32 add as reference) into LDS
    {
        const float4* wg4 = (const float4*)(weights + (size_t)gb * 1024);
#pragma unroll
        for (int i = 0; i < 4; ++i) {
            const int idx = lane + (i << 6);      // 0..255 float4s
            const float4 v = wg4[idx];
            const int fi = idx << 2;
            const int rr = fi >> 5, cc = fi & 31;
            float* p = &wl[rr * WP + cc];
            p[0] = v.x + EPSV; p[1] = v.y + EPSV; p[2] = v.z + EPSV; p[3] = v.w + EPSV;
        }
    }
    // INF-fill dist incl. halo ring
    {
        const float4 inf4 = make_float4(INFV, INFV, INFV, INFV);
        float4* df = (float4*)&g[0];              // 298 float4s
#pragma unroll
        for (int i = 0; i < 5; ++i) {
            const int idx = lane + (i << 6);
            if (idx < 298) df[idx] = inf4;
        }
    }
    __syncthreads();

    const int sr = source[2 * gb], sc = source[2 * gb + 1];
    if (lane == 0)
        g[(sr + 1) * DP + sc + 1] = wl[sr * WP + sc];

    // register-cached weights for both orientations (never change)
    float w_r[16], w_c[16];
#pragma unroll
    for (int j = 0; j < 16; ++j) {
        w_r[j] = wl[line * WP + (16 * h + j)];        // (row=line, col=16h+j)
        w_c[j] = wl[(16 * h + j) * WP + line];        // (row=16h+j, col=line)
    }
    __syncthreads();

    const int rbase = (line + 1) * DP + 16 * h;       // cell (line, 16h-1)
    const int cbase = (16 * h) * DP + line + 1;       // cell (16h-1, line)

    // 4-orientation chunked fast sweeping: row L->R, col T->B, row R->L, col B->T
    for (int it = 0; it < 1024; ++it) {
        __asm__ __volatile__("" ::: "memory");        // no reg-caching of g across passes
        float mx;
        switch (it & 3) {
            case 0:  mx = subpass<1,  DP, true >(g, rbase, w_r); break;
            case 1:  mx = subpass<DP, 1,  true >(g, cbase, w_c); break;
            case 2:  mx = subpass<1,  DP, false>(g, rbase, w_r); break;
            default: mx = subpass<DP, 1,  false>(g, cbase, w_c); break;
        }
        if (__ballot(mx > 0.0f) == 0ULL) break;       // full no-change pass = fixed point
    }
    __syncthreads();

    // Greedy backtrack, lane 0. Halo ring = INFV matches reference's
    // where(valid,.,INF); strict '<' in OFFS order = jnp.argmin tie-break.
    if (lane == 0) {
        const int drr[8] = {-1, -1, -1,  0, 0,  1, 1, 1};
        const int dcc[8] = {-1,  0,  1, -1, 1, -1, 0, 1};
        int pr = target[2 * gb], pc = target[2 * gb + 1];
        float* ob = out + (size_t)gb * 1024;
        for (int step = 0; step < 1024; ++step) {
            ob[pr * 32 + pc] = 1.0f;
            if (pr == sr && pc == sc) break;
            float best = INFV; int bj = 0;
#pragma unroll
            for (int j = 0; j < 8; ++j) {
                const float v = g[(pr + drr[j] + 1) * DP + (pc + dcc[j] + 1)];
                if (v < best) { best = v; bj = j; }
            }
            pr += drr[bj];
            pc += dcc[bj];
        }
    }
}

extern "C" void kernel_launch(void* const* d_in, const int* in_sizes, int n_in,
                              void* d_out, int out_size, void* d_ws, size_t ws_size,
                              hipStream_t stream) {
    const float* weights = (const float*)d_in[0];
    const int*   source  = (const int*)d_in[1];
    const int*   target  = (const int*)d_in[2];
    float*       out     = (float*)d_out;
    const int B = in_sizes[0] / 1024;
    bbastar_kernel<<<B, 64, 0, stream>>>(weights, source, target, out);
}